// Round 5
// baseline (239.871 us; speedup 1.0000x reference)
//
#include <hip/hip_runtime.h>
#include <stdint.h>

// VQ-VAE forward on MI355X — round 5.
// d_out (fp32): out[4194304] | loss[1] | perplexity[1] | idx_as_float[16384]
//
// prep_w : weight -> fp16 chunk-packed (32 codes = 16KB, granule-swizzled);
//          hw[n] = 1024 - |w|^2/2 (MFMA C-init bias); zero counts/loss/ticket.
// gemm   : 4-wave blocks, 256 rows, shared quad-buffered LDS chunks staged by
//          global_load_lds(16B); RAW s_barrier + per-wave partial vmcnt pacing
//          (no __syncthreads in loop). 8 splits XCD-pinned (512KB per-XCD L2).
//          Code stream: 1 MB/CU total (4x less than r3, 8x less per-row than r4).
// finish : prune candidates by approx key, fp64 rescore -> exact idx, counts,
//          loss; gather weight[idx] -> out; LAST BLOCK computes perplexity+loss.

#define M_TOTAL 16384
#define N_CODES 8192
#define KDIM    256
#define SPATIAL 4096
#define NSPLIT  8
#define CODES_PER_SPLIT  1024
#define CHUNK_CODES      32
#define CHUNKS_PER_SPLIT 32
#define CHUNK_HALFS      8192      // 32 codes * 256 dims
#define CHUNK_BYTES      16384

typedef _Float16 v8hf __attribute__((ext_vector_type(8)));
typedef _Float16 v4hf __attribute__((ext_vector_type(4)));
typedef float    v4f  __attribute__((ext_vector_type(4)));

// ---------------------------------------------------------------- prep_w (+init)
__global__ __launch_bounds__(256) void prep_w_kernel(
    const float* __restrict__ w, _Float16* __restrict__ wpk,
    float* __restrict__ hw_arr, int* __restrict__ counts,
    double* __restrict__ loss_acc, int* __restrict__ done_ctr)
{
    const int t = threadIdx.x;
    const int n = blockIdx.x * 4 + (t >> 6);
    const int lane = t & 63;
    v4f v = ((const v4f*)(w + (size_t)n * KDIM))[lane];
    v4hf hv;
    float s = 0.0f;
#pragma unroll
    for (int j = 0; j < 4; j++) {
        float f = v[j];
        s += f * f;
        hv[j] = (_Float16)f;
    }
    const int chunk = n >> 5;
    const int row   = n & 31;
    const int gg    = (lane >> 1) ^ (n & 7);           // 16B-granule swizzle
    size_t off = (size_t)chunk * CHUNK_HALFS + row * 256 + gg * 8 + (lane & 1) * 4;
    *(v4hf*)(wpk + off) = hv;
#pragma unroll
    for (int o = 32; o >= 1; o >>= 1) s += __shfl_xor(s, o);
    if (lane == 0) hw_arr[n] = 1024.0f - 0.5f * s;     // acc = hw + dot > 0
    const int gi = blockIdx.x * 256 + t;
    if (gi < N_CODES) counts[gi] = 0;
    if (gi == 0) { *loss_acc = 0.0; *done_ctr = 0; }
}

// ---------------------------------------------------------------- top-2 MAX merge
__device__ __forceinline__ void top2max_merge(uint32_t& v1, int& i1, uint32_t& v2, int& i2,
                                              uint32_t o1, int oi1, uint32_t o2, int oi2) {
    bool ob = (o1 > v1) || (o1 == v1 && oi1 < i1);
    uint32_t n1v, n2v; int n1i, n2i;
    if (ob) {
        bool t2 = (v1 > o2) || (v1 == o2 && i1 < oi2);
        n1v = o1; n1i = oi1;
        n2v = t2 ? v1 : o2; n2i = t2 ? i1 : oi2;
    } else {
        bool t2 = (o1 > v2) || (o1 == v2 && oi1 < i2);
        n1v = v1; n1i = i1;
        n2v = t2 ? o1 : v2; n2i = t2 ? oi1 : i2;
    }
    v1 = n1v; i1 = n1i; v2 = n2v; i2 = n2i;
}

// ---------------------------------------------------------------- gemm
// grid 512 = 64 row-blocks x 8 splits; block = 4 waves (256 thr), 256 rows.
__global__ __launch_bounds__(256, 2) void gemm_kernel(
    const float* __restrict__ z,
    const _Float16* __restrict__ wpk,
    const float* __restrict__ hw_arr,
    int4* __restrict__ candbuf)          // [M_TOTAL][8] = {k1,n1,k2,n2}
{
    __shared__ __align__(16) _Float16 lds[4][CHUNK_HALFS];   // 4 x 16KB
    __shared__ float hw_lds[CODES_PER_SPLIT];                // 4KB

    const int bid   = blockIdx.x;
    const int split = bid & 7;
    const int rb    = bid >> 3;            // 0..63
    const int i0    = rb * 256;
    const int b     = i0 >> 12;
    const int s0    = i0 & (SPATIAL - 1);
    const int tid   = threadIdx.x;
    const int wave  = tid >> 6;
    const int lane  = tid & 63;
    const int r     = lane & 15;
    const int q     = lane >> 4;

    const char* wsplit = (const char*)wpk + (size_t)split * (CODES_PER_SPLIT * KDIM * 2);
    auto stage = [&](int chunk, int buf) {
        const char* gb = wsplit + (size_t)chunk * CHUNK_BYTES + tid * 16;
        _Float16* lb = &lds[buf][tid * 8];
#pragma unroll
        for (int j = 0; j < 4; j++) {
            __builtin_amdgcn_global_load_lds(
                (const __attribute__((address_space(1))) void*)(gb + j * 4096),
                (__attribute__((address_space(3))) void*)(lb + j * 2048), 16, 0, 0);
        }
    };
    stage(0, 0); stage(1, 1); stage(2, 2);

    // one-time hw bias -> LDS
    {
        v4f h = *(const v4f*)(hw_arr + split * CODES_PER_SPLIT + tid * 4);
        *(v4f*)&hw_lds[tid * 4] = h;
    }

    // ---- A fragments: 4 m-tiles x 8 ks (128 VGPRs); overlaps stage latency ----
    v8hf a[4][8];
    {
        const float* zb = z + ((size_t)b << 20) + (size_t)(s0 + wave * 64 + r);
#pragma unroll
        for (int mt = 0; mt < 4; mt++) {
#pragma unroll
            for (int ks = 0; ks < 8; ks++) {
                const int kbase = ks * 32 + q * 8;
#pragma unroll
                for (int j = 0; j < 8; j++)
                    a[mt][ks][j] = (_Float16)zb[((size_t)(kbase + j) << 12) + mt * 16];
            }
        }
    }

    uint32_t k1[4][4], k2[4][4];
#pragma unroll
    for (int mt = 0; mt < 4; mt++)
#pragma unroll
    for (int g = 0; g < 4; g++) { k1[mt][g] = 0u; k2[mt][g] = 0u; }

    const int swz = r & 7;

    __syncthreads();   // one-time full drain: hw_lds + prologue stages visible

    auto body = [&](int it, int buf) {
        const float hw0 = hw_lds[it * 32 + r];
        const float hw1 = hw_lds[it * 32 + 16 + r];
        v4f acc[4][2];
#pragma unroll
        for (int mt = 0; mt < 4; mt++) {
            acc[mt][0] = (v4f){hw0, hw0, hw0, hw0};
            acc[mt][1] = (v4f){hw1, hw1, hw1, hw1};
        }
        const _Float16* L = &lds[buf][0];
#pragma unroll
        for (int st = 0; st < 2; st++) {
            const int rowoff = (st * 16 + r) * 256;
#pragma unroll
            for (int ks = 0; ks < 8; ks++) {
                const int gran = ((ks << 2) | q) ^ swz;
                v8hf bh = *(const v8hf*)(L + rowoff + (gran << 3));
#pragma unroll
                for (int mt = 0; mt < 4; mt++)
                    acc[mt][st] = __builtin_amdgcn_mfma_f32_16x16x32_f16(a[mt][ks], bh, acc[mt][st], 0, 0, 0);
            }
        }
        // distance = 2048 - 2*acc; larger acc = better -> top-2 MAX of packed key
#pragma unroll
        for (int st = 0; st < 2; st++) {
            const uint32_t tag = (uint32_t)(it * 2 + st);
#pragma unroll
            for (int mt = 0; mt < 4; mt++)
#pragma unroll
            for (int g = 0; g < 4; g++) {
                uint32_t key = (__float_as_uint(acc[mt][st][g]) & 0xFFFFFFC0u) | tag;
                uint32_t o1 = k1[mt][g], o2 = k2[mt][g];
                uint32_t hi = key > o2 ? key : o2;
                k2[mt][g] = hi < o1 ? hi : o1;      // med3(key, k1, k2)
                k1[mt][g] = key > o1 ? key : o1;
            }
        }
    };

#pragma unroll 1
    for (int it = 0; it < CHUNKS_PER_SPLIT - 2; it++) {
        asm volatile("s_waitcnt vmcnt(8)" ::: "memory");   // own chunk-it loads retired
        asm volatile("s_barrier" ::: "memory");            // all waves confirmed chunk it
        if (it + 3 < CHUNKS_PER_SPLIT) stage(it + 3, (it + 3) & 3);
        body(it, it & 3);
    }
    asm volatile("s_waitcnt vmcnt(4)" ::: "memory");
    asm volatile("s_barrier" ::: "memory");
    body(CHUNKS_PER_SPLIT - 2, (CHUNKS_PER_SPLIT - 2) & 3);
    asm volatile("s_waitcnt vmcnt(0)" ::: "memory");
    asm volatile("s_barrier" ::: "memory");
    body(CHUNKS_PER_SPLIT - 1, (CHUNKS_PER_SPLIT - 1) & 3);

    // decode n, cross-lane top-2 over the 16 r-lanes, write per-split candidates
    const int nsbase = split * CODES_PER_SPLIT + r;
#pragma unroll
    for (int mt = 0; mt < 4; mt++) {
#pragma unroll
        for (int g = 0; g < 4; g++) {
            uint32_t K1 = k1[mt][g], K2 = k2[mt][g];
            int n1 = nsbase + (int)((K1 & 63u) << 4);
            int n2 = nsbase + (int)((K2 & 63u) << 4);
#pragma unroll
            for (int off = 1; off < 16; off <<= 1) {
                uint32_t o1 = __shfl_xor(K1, off);
                int     on1 = __shfl_xor(n1, off);
                uint32_t o2 = __shfl_xor(K2, off);
                int     on2 = __shfl_xor(n2, off);
                top2max_merge(K1, n1, K2, n2, o1, on1, o2, on2);
            }
            if (r == 0) {
                const int row = i0 + wave * 64 + mt * 16 + q * 4 + g;
                candbuf[(size_t)row * 8 + split] = make_int4((int)K1, n1, (int)K2, n2);
            }
        }
    }
}

// ---------------------------------------------------------------- finish (+finalize)
__global__ __launch_bounds__(256) void finish_kernel(
    const float* __restrict__ z, const float* __restrict__ weight,
    const int4* __restrict__ candbuf,
    int* __restrict__ counts, double* __restrict__ loss_acc,
    int* __restrict__ done_ctr,
    float* __restrict__ out, float* __restrict__ out_scalars,
    float* __restrict__ out_idx_f)
{
    __shared__ int4  s_cand[32][8];
    __shared__ float s_zw[32][KDIM + 1];
    __shared__ int   s_fi[32];
    __shared__ double s_red[4];
    __shared__ int   s_last;

    const int i0 = blockIdx.x * 32;
    const int b  = i0 >> 12;
    const int s0 = i0 & (SPATIAL - 1);
    const int t  = threadIdx.x;

    s_cand[t >> 3][t & 7] = candbuf[(size_t)(i0 + (t >> 3)) * 8 + (t & 7)];

    for (int e = t; e < 32 * KDIM; e += 256) {         // z tile: coalesced -> LDS
        const int c = e >> 5, rr = e & 31;
        s_zw[rr][c] = z[((size_t)b << 20) + ((size_t)c << 12) + s0 + rr];
    }
    __syncthreads();

    const int row = t >> 3, seg = t & 7;
    float zs[32];
#pragma unroll
    for (int j = 0; j < 32; j++) zs[j] = s_zw[row][seg * 32 + j];

    float da[16];
    float dmin_a = 3.4e38f;
#pragma unroll
    for (int sp = 0; sp < 8; sp++) {
        int4 c = s_cand[row][sp];
        da[sp * 2]     = 2048.0f - 2.0f * __uint_as_float((uint32_t)c.x & 0xFFFFFFC0u);
        da[sp * 2 + 1] = 2048.0f - 2.0f * __uint_as_float((uint32_t)c.z & 0xFFFFFFC0u);
        dmin_a = fminf(dmin_a, fminf(da[sp * 2], da[sp * 2 + 1]));
    }
    const float cutoff = dmin_a + 0.5f;

    double dbest = 1e300; int nbest = 0x7fffffff;
#pragma unroll 1
    for (int c = 0; c < 16; c++) {
        if (da[c] > cutoff) continue;
        int4 cc = s_cand[row][c >> 1];
        const int n = (c & 1) ? cc.w : cc.y;
        const float* wr = weight + (size_t)n * KDIM + seg * 32;
        double d = 0.0;
#pragma unroll
        for (int j = 0; j < 32; j++) {
            double df = (double)zs[j] - (double)wr[j];
            d += df * df;
        }
#pragma unroll
        for (int o = 1; o < 8; o <<= 1) d += __shfl_xor(d, o);
        if (d < dbest || (d == dbest && n < nbest)) { dbest = d; nbest = n; }
    }

    double lsum = 0.0;
    if (seg == 0) {
        s_fi[row] = nbest;
        out_idx_f[i0 + row] = (float)nbest;
        atomicAdd(&counts[nbest], 1);
        lsum = dbest;
    }
#pragma unroll
    for (int o = 1; o < 64; o <<= 1) lsum += __shfl_xor(lsum, o);
    if ((t & 63) == 0) s_red[t >> 6] = lsum;
    __syncthreads();
    if (t == 0) atomicAdd(loss_acc, s_red[0] + s_red[1] + s_red[2] + s_red[3]);

    // gather weight[fi] -> LDS -> transposed coalesced write
    for (int e = t; e < 32 * KDIM; e += 256) {
        const int rr = e >> 8, c = e & 255;
        s_zw[rr][c] = weight[(size_t)s_fi[rr] * KDIM + c];
    }
    __syncthreads();
    const int m = t & 31, c0 = t >> 5;
    const size_t obase = ((size_t)b << 20) + (size_t)(s0 + m);
    for (int c = c0; c < KDIM; c += 8)
        out[obase + ((size_t)c << 12)] = s_zw[m][c];

    // ---- last-block finalize: perplexity + loss scale ----
    if (t == 0) {
        __threadfence();
        int old = __hip_atomic_fetch_add(done_ctr, 1, __ATOMIC_ACQ_REL,
                                         __HIP_MEMORY_SCOPE_AGENT);
        s_last = (old == (int)gridDim.x - 1);
    }
    __syncthreads();
    if (s_last) {
        double s = 0.0;
        for (int n = t; n < N_CODES; n += 256) {
            int c = __hip_atomic_load(&counts[n], __ATOMIC_RELAXED,
                                      __HIP_MEMORY_SCOPE_AGENT);
            double p = (double)c / (double)M_TOTAL;
            s -= p * log(p + 1e-10);
        }
#pragma unroll
        for (int o = 32; o >= 1; o >>= 1) s += __shfl_xor(s, o);
        if ((t & 63) == 0) s_red[t >> 6] = s;
        __syncthreads();
        if (t == 0) {
            double tot = s_red[0] + s_red[1] + s_red[2] + s_red[3];
            double l = __hip_atomic_load(loss_acc, __ATOMIC_RELAXED,
                                         __HIP_MEMORY_SCOPE_AGENT);
            out_scalars[0] = (float)(0.25 * l / (double)(M_TOTAL * KDIM));
            out_scalars[1] = (float)exp(tot);
        }
    }
}

// ---------------------------------------------------------------- launch
extern "C" void kernel_launch(void* const* d_in, const int* in_sizes, int n_in,
                              void* d_out, int out_size, void* d_ws, size_t ws_size,
                              hipStream_t stream) {
    const float* z      = (const float*)d_in[0];   // 4*256*16*16*16 = 16.8 MB
    const float* weight = (const float*)d_in[1];   // 8192*256 = 8.4 MB
    float* out = (float*)d_out;

    size_t off = 0;
    auto carve = [&](size_t bytes) {
        void* p = (char*)d_ws + off;
        off += (bytes + 255) & ~(size_t)255;
        return p;
    };
    _Float16* wpk     = (_Float16*)carve((size_t)N_CODES * KDIM * 2);   // 4 MB
    float*    hw_arr  = (float*)   carve((size_t)N_CODES * 4);
    int4*     candbuf = (int4*)    carve((size_t)M_TOTAL * 8 * 16);     // 2 MB
    int*      counts  = (int*)     carve((size_t)N_CODES * 4);
    double*   lossac  = (double*)  carve(16);
    int*      donec   = (int*)     carve(16);

    float* out_scalars = out + (size_t)4 * KDIM * SPATIAL;   // [loss, perplexity]
    float* out_idx_f   = out_scalars + 2;                    // 16384 idx as float

    prep_w_kernel<<<dim3(N_CODES / 4), dim3(256), 0, stream>>>(
        weight, wpk, hw_arr, counts, lossac, donec);
    gemm_kernel<<<dim3(64 * NSPLIT), dim3(256), 0, stream>>>(z, wpk, hw_arr, candbuf);
    finish_kernel<<<dim3(M_TOTAL / 32), dim3(256), 0, stream>>>(
        z, weight, candbuf, counts, lossac, donec, out, out_scalars, out_idx_f);
}

// Round 6
// 219.813 us; speedup vs baseline: 1.0913x; 1.0913x over previous
//
#include <hip/hip_runtime.h>
#include <stdint.h>

// VQ-VAE forward on MI355X — round 6.
// d_out (fp32): out[4194304] | loss[1] | perplexity[1] | idx_as_float[16384]
//
// prep   : (one dispatch) codes -> fp16 chunk-packed + swizzled wpk, hw bias;
//          z -> fp16 A-fragment-layout zfrag (read once, coalesced b128 in gemm);
//          zero counts/loss/ticket.
// gemm   : 4-wave blocks, 128 rows, 8 splits XCD-pinned; double-buffered LDS
//          (2x16KB) via global_load_lds(16B) + plain __syncthreads; 4 blocks/CU
//          -> 16 waves/CU (was 8 in r3-r5: the occupancy wall). Packed-key
//          top-2 per split.
// finish : prune candidates by approx key, fp64 rescore -> exact idx, counts,
//          loss; gather weight[idx] -> out; LAST BLOCK computes perplexity+loss.

#define M_TOTAL 16384
#define N_CODES 8192
#define KDIM    256
#define SPATIAL 4096
#define NSPLIT  8
#define CODES_PER_SPLIT  1024
#define CHUNK_CODES      32
#define CHUNKS_PER_SPLIT 32
#define CHUNK_HALFS      8192      // 32 codes * 256 dims
#define CHUNK_BYTES      16384

typedef _Float16 v8hf __attribute__((ext_vector_type(8)));
typedef _Float16 v4hf __attribute__((ext_vector_type(4)));
typedef float    v4f  __attribute__((ext_vector_type(4)));

// ---------------------------------------------------------------- prep (w + z + init)
// blocks [0,2048): codebook -> wpk (chunk-packed, granule-swizzled) + hw bias.
// blocks [2048,2304): z -> zfrag in A-fragment layout:
//   zfrag half-index = ((g16*8 + ks)*64 + lane)*8 + j, where lane=(q<<4)|r,
//   row = g16*16 + r, k = ks*32 + q*8 + j.
__global__ __launch_bounds__(256) void prep_kernel(
    const float* __restrict__ w, const float* __restrict__ z,
    _Float16* __restrict__ wpk, float* __restrict__ hw_arr,
    _Float16* __restrict__ zfrag,
    int* __restrict__ counts, double* __restrict__ loss_acc,
    int* __restrict__ done_ctr)
{
    const int bid = blockIdx.x;
    const int t = threadIdx.x;
    if (bid < 2048) {
        const int n = bid * 4 + (t >> 6);
        const int lane = t & 63;
        v4f v = ((const v4f*)(w + (size_t)n * KDIM))[lane];
        v4hf hv;
        float s = 0.0f;
#pragma unroll
        for (int j = 0; j < 4; j++) {
            float f = v[j];
            s += f * f;
            hv[j] = (_Float16)f;
        }
        const int chunk = n >> 5;
        const int row   = n & 31;
        const int gg    = (lane >> 1) ^ (n & 7);           // 16B-granule swizzle
        size_t off = (size_t)chunk * CHUNK_HALFS + row * 256 + gg * 8 + (lane & 1) * 4;
        *(v4hf*)(wpk + off) = hv;
#pragma unroll
        for (int o = 32; o >= 1; o >>= 1) s += __shfl_xor(s, o);
        if (lane == 0) hw_arr[n] = 1024.0f - 0.5f * s;     // acc = hw + dot > 0
        const int gi = bid * 4 + (t >> 6);                 // reuse for init
        if (t < 4 && false) {}
        const int ci = bid * 4 + (t & 3);                  // 4 counts per block
        if ((t >> 2) == 0) counts[ci] = 0;
        if (bid == 0 && t == 0) { *loss_acc = 0.0; *done_ctr = 0; }
        (void)gi;
    } else {
        const int g16  = (bid - 2048) * 4 + (t >> 6);      // row-group 0..1023
        const int lane = t & 63;
        const int r    = lane & 15;
        const int q    = lane >> 4;
        const int row  = g16 * 16 + r;
        const int b    = row >> 12;
        const int s    = row & (SPATIAL - 1);
        const float* zb = z + ((size_t)b << 20) + s;
#pragma unroll
        for (int ks = 0; ks < 8; ks++) {
            v8hf o;
#pragma unroll
            for (int j = 0; j < 8; j++)
                o[j] = (_Float16)zb[(size_t)(ks * 32 + q * 8 + j) << 12];
            *(v8hf*)(zfrag + ((size_t)(g16 * 8 + ks) * 64 + lane) * 8) = o;
        }
    }
}

// ---------------------------------------------------------------- top-2 MAX merge
__device__ __forceinline__ void top2max_merge(uint32_t& v1, int& i1, uint32_t& v2, int& i2,
                                              uint32_t o1, int oi1, uint32_t o2, int oi2) {
    bool ob = (o1 > v1) || (o1 == v1 && oi1 < i1);
    uint32_t n1v, n2v; int n1i, n2i;
    if (ob) {
        bool t2 = (v1 > o2) || (v1 == o2 && i1 < oi2);
        n1v = o1; n1i = oi1;
        n2v = t2 ? v1 : o2; n2i = t2 ? i1 : oi2;
    } else {
        bool t2 = (o1 > v2) || (o1 == v2 && oi1 < i2);
        n1v = v1; n1i = i1;
        n2v = t2 ? o1 : v2; n2i = t2 ? oi1 : i2;
    }
    v1 = n1v; i1 = n1i; v2 = n2v; i2 = n2i;
}

// ---------------------------------------------------------------- gemm
// grid 1024 = 128 rb x 8 splits; block = 4 waves (256 thr), 128 rows (32/wave).
// LDS 36KB -> 4 blocks/CU -> 16 waves/CU.
__global__ __launch_bounds__(256, 4) void gemm_kernel(
    const _Float16* __restrict__ zfrag,
    const _Float16* __restrict__ wpk,
    const float* __restrict__ hw_arr,
    int4* __restrict__ candbuf)          // [M_TOTAL][8] = {k1,n1,k2,n2}
{
    __shared__ __align__(16) _Float16 lds[2][CHUNK_HALFS];   // 2 x 16KB
    __shared__ float hw_lds[CODES_PER_SPLIT];                // 4KB

    const int bid   = blockIdx.x;
    const int split = bid & 7;
    const int rb    = bid >> 3;            // 0..127
    const int i0    = rb * 128;
    const int tid   = threadIdx.x;
    const int wave  = tid >> 6;
    const int lane  = tid & 63;
    const int r     = lane & 15;
    const int q     = lane >> 4;

    const char* wsplit = (const char*)wpk + (size_t)split * (CODES_PER_SPLIT * KDIM * 2);
    auto stage = [&](int chunk, int buf) {
        const char* gb = wsplit + (size_t)chunk * CHUNK_BYTES + tid * 16;
        _Float16* lb = &lds[buf][tid * 8];
#pragma unroll
        for (int j = 0; j < 4; j++) {
            __builtin_amdgcn_global_load_lds(
                (const __attribute__((address_space(1))) void*)(gb + j * 4096),
                (__attribute__((address_space(3))) void*)(lb + j * 2048), 16, 0, 0);
        }
    };
    stage(0, 0);

    // one-time hw bias -> LDS
    {
        v4f h = *(const v4f*)(hw_arr + split * CODES_PER_SPLIT + tid * 4);
        *(v4f*)&hw_lds[tid * 4] = h;
    }

    // ---- A fragments from zfrag: 2 m-tiles x 8 ks, coalesced b128 (64 VGPRs) ----
    v8hf a[2][8];
    {
        const int g16 = (i0 + wave * 32) >> 4;      // rb*8 + wave*2
#pragma unroll
        for (int mt = 0; mt < 2; mt++) {
#pragma unroll
            for (int ks = 0; ks < 8; ks++)
                a[mt][ks] = *(const v8hf*)(zfrag +
                    ((size_t)((g16 + mt) * 8 + ks) * 64 + lane) * 8);
        }
    }

    uint32_t k1[2][4], k2[2][4];
#pragma unroll
    for (int mt = 0; mt < 2; mt++)
#pragma unroll
    for (int g = 0; g < 4; g++) { k1[mt][g] = 0u; k2[mt][g] = 0u; }

    const int swz = r & 7;

    __syncthreads();   // stage(0) + hw_lds visible

#pragma unroll 1
    for (int it = 0; it < CHUNKS_PER_SPLIT; it++) {
        const int buf = it & 1;
        if (it + 1 < CHUNKS_PER_SPLIT) stage(it + 1, buf ^ 1);

        const float hw0 = hw_lds[it * 32 + r];
        const float hw1 = hw_lds[it * 32 + 16 + r];
        v4f acc[2][2];
#pragma unroll
        for (int mt = 0; mt < 2; mt++) {
            acc[mt][0] = (v4f){hw0, hw0, hw0, hw0};
            acc[mt][1] = (v4f){hw1, hw1, hw1, hw1};
        }
        const _Float16* L = &lds[buf][0];
#pragma unroll
        for (int st = 0; st < 2; st++) {
            const int rowoff = (st * 16 + r) * 256;
#pragma unroll
            for (int ks = 0; ks < 8; ks++) {
                const int gran = ((ks << 2) | q) ^ swz;
                v8hf bh = *(const v8hf*)(L + rowoff + (gran << 3));
#pragma unroll
                for (int mt = 0; mt < 2; mt++)
                    acc[mt][st] = __builtin_amdgcn_mfma_f32_16x16x32_f16(a[mt][ks], bh, acc[mt][st], 0, 0, 0);
            }
        }
        // distance = 2048 - 2*acc -> larger acc = better; packed-key top-2 MAX
#pragma unroll
        for (int st = 0; st < 2; st++) {
            const uint32_t tag = (uint32_t)(it * 2 + st);
#pragma unroll
            for (int mt = 0; mt < 2; mt++)
#pragma unroll
            for (int g = 0; g < 4; g++) {
                uint32_t key = (__float_as_uint(acc[mt][st][g]) & 0xFFFFFFC0u) | tag;
                uint32_t o1 = k1[mt][g], o2 = k2[mt][g];
                uint32_t hi = key > o2 ? key : o2;
                k2[mt][g] = hi < o1 ? hi : o1;      // med3(key, k1, k2)
                k1[mt][g] = key > o1 ? key : o1;
            }
        }
        __syncthreads();   // all waves done with buf; stage(it+1) drained
    }

    // decode n, cross-lane top-2 over the 16 r-lanes, write per-split candidates
    const int nsbase = split * CODES_PER_SPLIT + r;
#pragma unroll
    for (int mt = 0; mt < 2; mt++) {
#pragma unroll
        for (int g = 0; g < 4; g++) {
            uint32_t K1 = k1[mt][g], K2 = k2[mt][g];
            int n1 = nsbase + (int)((K1 & 63u) << 4);
            int n2 = nsbase + (int)((K2 & 63u) << 4);
#pragma unroll
            for (int off = 1; off < 16; off <<= 1) {
                uint32_t o1 = __shfl_xor(K1, off);
                int     on1 = __shfl_xor(n1, off);
                uint32_t o2 = __shfl_xor(K2, off);
                int     on2 = __shfl_xor(n2, off);
                top2max_merge(K1, n1, K2, n2, o1, on1, o2, on2);
            }
            if (r == 0) {
                const int row = i0 + wave * 32 + mt * 16 + q * 4 + g;
                candbuf[(size_t)row * 8 + split] = make_int4((int)K1, n1, (int)K2, n2);
            }
        }
    }
}

// ---------------------------------------------------------------- finish (+finalize)
__global__ __launch_bounds__(256) void finish_kernel(
    const float* __restrict__ z, const float* __restrict__ weight,
    const int4* __restrict__ candbuf,
    int* __restrict__ counts, double* __restrict__ loss_acc,
    int* __restrict__ done_ctr,
    float* __restrict__ out, float* __restrict__ out_scalars,
    float* __restrict__ out_idx_f)
{
    __shared__ int4  s_cand[32][8];
    __shared__ float s_zw[32][KDIM + 1];
    __shared__ int   s_fi[32];
    __shared__ double s_red[4];
    __shared__ int   s_last;

    const int i0 = blockIdx.x * 32;
    const int b  = i0 >> 12;
    const int s0 = i0 & (SPATIAL - 1);
    const int t  = threadIdx.x;

    s_cand[t >> 3][t & 7] = candbuf[(size_t)(i0 + (t >> 3)) * 8 + (t & 7)];

    for (int e = t; e < 32 * KDIM; e += 256) {         // z tile: coalesced -> LDS
        const int c = e >> 5, rr = e & 31;
        s_zw[rr][c] = z[((size_t)b << 20) + ((size_t)c << 12) + s0 + rr];
    }
    __syncthreads();

    const int row = t >> 3, seg = t & 7;
    float zs[32];
#pragma unroll
    for (int j = 0; j < 32; j++) zs[j] = s_zw[row][seg * 32 + j];

    float da[16];
    float dmin_a = 3.4e38f;
#pragma unroll
    for (int sp = 0; sp < 8; sp++) {
        int4 c = s_cand[row][sp];
        da[sp * 2]     = 2048.0f - 2.0f * __uint_as_float((uint32_t)c.x & 0xFFFFFFC0u);
        da[sp * 2 + 1] = 2048.0f - 2.0f * __uint_as_float((uint32_t)c.z & 0xFFFFFFC0u);
        dmin_a = fminf(dmin_a, fminf(da[sp * 2], da[sp * 2 + 1]));
    }
    const float cutoff = dmin_a + 0.5f;

    double dbest = 1e300; int nbest = 0x7fffffff;
#pragma unroll 1
    for (int c = 0; c < 16; c++) {
        if (da[c] > cutoff) continue;
        int4 cc = s_cand[row][c >> 1];
        const int n = (c & 1) ? cc.w : cc.y;
        const float* wr = weight + (size_t)n * KDIM + seg * 32;
        double d = 0.0;
#pragma unroll
        for (int j = 0; j < 32; j++) {
            double df = (double)zs[j] - (double)wr[j];
            d += df * df;
        }
#pragma unroll
        for (int o = 1; o < 8; o <<= 1) d += __shfl_xor(d, o);
        if (d < dbest || (d == dbest && n < nbest)) { dbest = d; nbest = n; }
    }

    double lsum = 0.0;
    if (seg == 0) {
        s_fi[row] = nbest;
        out_idx_f[i0 + row] = (float)nbest;
        atomicAdd(&counts[nbest], 1);
        lsum = dbest;
    }
#pragma unroll
    for (int o = 1; o < 64; o <<= 1) lsum += __shfl_xor(lsum, o);
    if ((t & 63) == 0) s_red[t >> 6] = lsum;
    __syncthreads();
    if (t == 0) atomicAdd(loss_acc, s_red[0] + s_red[1] + s_red[2] + s_red[3]);

    // gather weight[fi] -> LDS -> transposed coalesced write
    for (int e = t; e < 32 * KDIM; e += 256) {
        const int rr = e >> 8, c = e & 255;
        s_zw[rr][c] = weight[(size_t)s_fi[rr] * KDIM + c];
    }
    __syncthreads();
    const int m = t & 31, c0 = t >> 5;
    const size_t obase = ((size_t)b << 20) + (size_t)(s0 + m);
    for (int c = c0; c < KDIM; c += 8)
        out[obase + ((size_t)c << 12)] = s_zw[m][c];

    // ---- last-block finalize: perplexity + loss scale ----
    if (t == 0) {
        __threadfence();
        int old = __hip_atomic_fetch_add(done_ctr, 1, __ATOMIC_ACQ_REL,
                                         __HIP_MEMORY_SCOPE_AGENT);
        s_last = (old == (int)gridDim.x - 1);
    }
    __syncthreads();
    if (s_last) {
        double s = 0.0;
        for (int n = t; n < N_CODES; n += 256) {
            int c = __hip_atomic_load(&counts[n], __ATOMIC_RELAXED,
                                      __HIP_MEMORY_SCOPE_AGENT);
            double p = (double)c / (double)M_TOTAL;
            s -= p * log(p + 1e-10);
        }
#pragma unroll
        for (int o = 32; o >= 1; o >>= 1) s += __shfl_xor(s, o);
        if ((t & 63) == 0) s_red[t >> 6] = s;
        __syncthreads();
        if (t == 0) {
            double tot = s_red[0] + s_red[1] + s_red[2] + s_red[3];
            double l = __hip_atomic_load(loss_acc, __ATOMIC_RELAXED,
                                         __HIP_MEMORY_SCOPE_AGENT);
            out_scalars[0] = (float)(0.25 * l / (double)(M_TOTAL * KDIM));
            out_scalars[1] = (float)exp(tot);
        }
    }
}

// ---------------------------------------------------------------- launch
extern "C" void kernel_launch(void* const* d_in, const int* in_sizes, int n_in,
                              void* d_out, int out_size, void* d_ws, size_t ws_size,
                              hipStream_t stream) {
    const float* z      = (const float*)d_in[0];   // 4*256*16*16*16 = 16.8 MB
    const float* weight = (const float*)d_in[1];   // 8192*256 = 8.4 MB
    float* out = (float*)d_out;

    size_t off = 0;
    auto carve = [&](size_t bytes) {
        void* p = (char*)d_ws + off;
        off += (bytes + 255) & ~(size_t)255;
        return p;
    };
    _Float16* wpk     = (_Float16*)carve((size_t)N_CODES * KDIM * 2);   // 4 MB
    float*    hw_arr  = (float*)   carve((size_t)N_CODES * 4);
    _Float16* zfrag   = (_Float16*)carve((size_t)M_TOTAL * KDIM * 2);   // 8 MB
    int4*     candbuf = (int4*)    carve((size_t)M_TOTAL * 8 * 16);     // 2 MB
    int*      counts  = (int*)     carve((size_t)N_CODES * 4);
    double*   lossac  = (double*)  carve(16);
    int*      donec   = (int*)     carve(16);

    float* out_scalars = out + (size_t)4 * KDIM * SPATIAL;   // [loss, perplexity]
    float* out_idx_f   = out_scalars + 2;                    // 16384 idx as float

    prep_kernel<<<dim3(2048 + 256), dim3(256), 0, stream>>>(
        weight, z, wpk, hw_arr, zfrag, counts, lossac, donec);
    gemm_kernel<<<dim3(128 * NSPLIT), dim3(256), 0, stream>>>(
        zfrag, wpk, hw_arr, candbuf);
    finish_kernel<<<dim3(M_TOTAL / 32), dim3(256), 0, stream>>>(
        z, weight, candbuf, counts, lossac, donec, out, out_scalars, out_idx_f);
}

// Round 7
// 219.174 us; speedup vs baseline: 1.0944x; 1.0029x over previous
//
#include <hip/hip_runtime.h>
#include <stdint.h>

// VQ-VAE forward on MI355X — round 7.
// d_out (fp32): out[4194304] | loss[1] | perplexity[1] | idx_as_float[16384]
//
// prep   : [blocks 0..2048) codebook -> fp16 chunk-packed + swizzled wpk + hw bias
//          + counts/loss/ticket init.
//          [blocks 2048..2304) z -> fp16 A-fragment zfrag via coalesced LDS
//          transpose (r6 did stride-16KB scalar gathers here — the aux sink).
// gemm   : UNCHANGED from r6 (85 µs, MfmaUtil 34%): 4-wave blocks, 128 rows,
//          8 XCD-pinned splits, dbuf LDS global_load_lds, 4 blocks/CU.
// finish : UNCHANGED from r6: prune + fp64 rescore -> exact idx, counts, loss,
//          gather; last block computes perplexity + loss.

#define M_TOTAL 16384
#define N_CODES 8192
#define KDIM    256
#define SPATIAL 4096
#define NSPLIT  8
#define CODES_PER_SPLIT  1024
#define CHUNK_CODES      32
#define CHUNKS_PER_SPLIT 32
#define CHUNK_HALFS      8192      // 32 codes * 256 dims
#define CHUNK_BYTES      16384

typedef _Float16 v8hf __attribute__((ext_vector_type(8)));
typedef _Float16 v4hf __attribute__((ext_vector_type(4)));
typedef _Float16 v2hf __attribute__((ext_vector_type(2)));
typedef float    v4f  __attribute__((ext_vector_type(4)));
typedef float    v2f  __attribute__((ext_vector_type(2)));

// ---------------------------------------------------------------- prep (w + z + init)
__global__ __launch_bounds__(256) void prep_kernel(
    const float* __restrict__ w, const float* __restrict__ z,
    _Float16* __restrict__ wpk, float* __restrict__ hw_arr,
    _Float16* __restrict__ zfrag,
    int* __restrict__ counts, double* __restrict__ loss_acc,
    int* __restrict__ done_ctr)
{
    const int bid = blockIdx.x;
    const int t = threadIdx.x;
    if (bid < 2048) {
        // ---- codebook: pack + swizzle + hw bias ----
        const int n = bid * 4 + (t >> 6);
        const int lane = t & 63;
        v4f v = ((const v4f*)(w + (size_t)n * KDIM))[lane];
        v4hf hv;
        float s = 0.0f;
#pragma unroll
        for (int j = 0; j < 4; j++) {
            float f = v[j];
            s += f * f;
            hv[j] = (_Float16)f;
        }
        const int chunk = n >> 5;
        const int row   = n & 31;
        const int gg    = (lane >> 1) ^ (n & 7);           // 16B-granule swizzle
        size_t off = (size_t)chunk * CHUNK_HALFS + row * 256 + gg * 8 + (lane & 1) * 4;
        *(v4hf*)(wpk + off) = hv;
#pragma unroll
        for (int o = 32; o >= 1; o >>= 1) s += __shfl_xor(s, o);
        if (lane == 0) hw_arr[n] = 1024.0f - 0.5f * s;     // acc = hw + dot > 0
        if (t < 4) counts[bid * 4 + t] = 0;
        if (bid == 0 && t == 0) { *loss_acc = 0.0; *done_ctr = 0; }
    } else {
        // ---- z -> zfrag (A-fragment layout) via LDS transpose ----
        __shared__ _Float16 tile[256][66];                 // 33.8 KB, pad 66
        const int rb = bid - 2048;                         // 0..255, 64 rows each
        const int i0 = rb * 64;
        const int b  = i0 >> 12;
        const int s0 = i0 & (SPATIAL - 1);

        // load: 8192 float2 pairs, coalesced 512B/wave; convert; LDS write b32
        const float* zb = z + ((size_t)b << 20) + s0;
#pragma unroll
        for (int i = 0; i < 32; i++) {
            const int e2 = i * 256 + t;                    // pair index 0..8191
            const int k  = e2 >> 5;                        // 0..255
            const int sl = (e2 & 31) * 2;                  // 0..62 even
            v2f f = *(const v2f*)(zb + ((size_t)k << 12) + sl);
            v2hf h; h[0] = (_Float16)f[0]; h[1] = (_Float16)f[1];
            *(v2hf*)&tile[k][sl] = h;
        }
        __syncthreads();

        // write: wave = g16-subgroup; coalesced 1KB v8hf stores
        const int wave = t >> 6;
        const int lane = t & 63;
        const int r    = lane & 15;
        const int q    = lane >> 4;
        const int g16  = rb * 4 + wave;
        const int row_l = wave * 16 + r;
#pragma unroll
        for (int ks = 0; ks < 8; ks++) {
            v8hf o;
#pragma unroll
            for (int j = 0; j < 8; j++)
                o[j] = tile[ks * 32 + q * 8 + j][row_l];
            *(v8hf*)(zfrag + ((size_t)(g16 * 8 + ks) * 64 + lane) * 8) = o;
        }
    }
}

// ---------------------------------------------------------------- top-2 MAX merge
__device__ __forceinline__ void top2max_merge(uint32_t& v1, int& i1, uint32_t& v2, int& i2,
                                              uint32_t o1, int oi1, uint32_t o2, int oi2) {
    bool ob = (o1 > v1) || (o1 == v1 && oi1 < i1);
    uint32_t n1v, n2v; int n1i, n2i;
    if (ob) {
        bool t2 = (v1 > o2) || (v1 == o2 && i1 < oi2);
        n1v = o1; n1i = oi1;
        n2v = t2 ? v1 : o2; n2i = t2 ? i1 : oi2;
    } else {
        bool t2 = (o1 > v2) || (o1 == v2 && oi1 < i2);
        n1v = v1; n1i = i1;
        n2v = t2 ? o1 : v2; n2i = t2 ? oi1 : i2;
    }
    v1 = n1v; i1 = n1i; v2 = n2v; i2 = n2i;
}

// ---------------------------------------------------------------- gemm (r6 verbatim)
__global__ __launch_bounds__(256, 4) void gemm_kernel(
    const _Float16* __restrict__ zfrag,
    const _Float16* __restrict__ wpk,
    const float* __restrict__ hw_arr,
    int4* __restrict__ candbuf)          // [M_TOTAL][8] = {k1,n1,k2,n2}
{
    __shared__ __align__(16) _Float16 lds[2][CHUNK_HALFS];   // 2 x 16KB
    __shared__ float hw_lds[CODES_PER_SPLIT];                // 4KB

    const int bid   = blockIdx.x;
    const int split = bid & 7;
    const int rb    = bid >> 3;            // 0..127
    const int i0    = rb * 128;
    const int tid   = threadIdx.x;
    const int wave  = tid >> 6;
    const int lane  = tid & 63;
    const int r     = lane & 15;
    const int q     = lane >> 4;

    const char* wsplit = (const char*)wpk + (size_t)split * (CODES_PER_SPLIT * KDIM * 2);
    auto stage = [&](int chunk, int buf) {
        const char* gb = wsplit + (size_t)chunk * CHUNK_BYTES + tid * 16;
        _Float16* lb = &lds[buf][tid * 8];
#pragma unroll
        for (int j = 0; j < 4; j++) {
            __builtin_amdgcn_global_load_lds(
                (const __attribute__((address_space(1))) void*)(gb + j * 4096),
                (__attribute__((address_space(3))) void*)(lb + j * 2048), 16, 0, 0);
        }
    };
    stage(0, 0);

    {
        v4f h = *(const v4f*)(hw_arr + split * CODES_PER_SPLIT + tid * 4);
        *(v4f*)&hw_lds[tid * 4] = h;
    }

    // A fragments from zfrag: 2 m-tiles x 8 ks, coalesced b128 (64 VGPRs)
    v8hf a[2][8];
    {
        const int g16 = (i0 + wave * 32) >> 4;      // rb*8 + wave*2
#pragma unroll
        for (int mt = 0; mt < 2; mt++) {
#pragma unroll
            for (int ks = 0; ks < 8; ks++)
                a[mt][ks] = *(const v8hf*)(zfrag +
                    ((size_t)((g16 + mt) * 8 + ks) * 64 + lane) * 8);
        }
    }

    uint32_t k1[2][4], k2[2][4];
#pragma unroll
    for (int mt = 0; mt < 2; mt++)
#pragma unroll
    for (int g = 0; g < 4; g++) { k1[mt][g] = 0u; k2[mt][g] = 0u; }

    const int swz = r & 7;

    __syncthreads();   // stage(0) + hw_lds visible

#pragma unroll 1
    for (int it = 0; it < CHUNKS_PER_SPLIT; it++) {
        const int buf = it & 1;
        if (it + 1 < CHUNKS_PER_SPLIT) stage(it + 1, buf ^ 1);

        const float hw0 = hw_lds[it * 32 + r];
        const float hw1 = hw_lds[it * 32 + 16 + r];
        v4f acc[2][2];
#pragma unroll
        for (int mt = 0; mt < 2; mt++) {
            acc[mt][0] = (v4f){hw0, hw0, hw0, hw0};
            acc[mt][1] = (v4f){hw1, hw1, hw1, hw1};
        }
        const _Float16* L = &lds[buf][0];
#pragma unroll
        for (int st = 0; st < 2; st++) {
            const int rowoff = (st * 16 + r) * 256;
#pragma unroll
            for (int ks = 0; ks < 8; ks++) {
                const int gran = ((ks << 2) | q) ^ swz;
                v8hf bh = *(const v8hf*)(L + rowoff + (gran << 3));
#pragma unroll
                for (int mt = 0; mt < 2; mt++)
                    acc[mt][st] = __builtin_amdgcn_mfma_f32_16x16x32_f16(a[mt][ks], bh, acc[mt][st], 0, 0, 0);
            }
        }
#pragma unroll
        for (int st = 0; st < 2; st++) {
            const uint32_t tag = (uint32_t)(it * 2 + st);
#pragma unroll
            for (int mt = 0; mt < 2; mt++)
#pragma unroll
            for (int g = 0; g < 4; g++) {
                uint32_t key = (__float_as_uint(acc[mt][st][g]) & 0xFFFFFFC0u) | tag;
                uint32_t o1 = k1[mt][g], o2 = k2[mt][g];
                uint32_t hi = key > o2 ? key : o2;
                k2[mt][g] = hi < o1 ? hi : o1;      // med3(key, k1, k2)
                k1[mt][g] = key > o1 ? key : o1;
            }
        }
        __syncthreads();
    }

    const int nsbase = split * CODES_PER_SPLIT + r;
#pragma unroll
    for (int mt = 0; mt < 2; mt++) {
#pragma unroll
        for (int g = 0; g < 4; g++) {
            uint32_t K1 = k1[mt][g], K2 = k2[mt][g];
            int n1 = nsbase + (int)((K1 & 63u) << 4);
            int n2 = nsbase + (int)((K2 & 63u) << 4);
#pragma unroll
            for (int off = 1; off < 16; off <<= 1) {
                uint32_t o1 = __shfl_xor(K1, off);
                int     on1 = __shfl_xor(n1, off);
                uint32_t o2 = __shfl_xor(K2, off);
                int     on2 = __shfl_xor(n2, off);
                top2max_merge(K1, n1, K2, n2, o1, on1, o2, on2);
            }
            if (r == 0) {
                const int row = i0 + wave * 32 + mt * 16 + q * 4 + g;
                candbuf[(size_t)row * 8 + split] = make_int4((int)K1, n1, (int)K2, n2);
            }
        }
    }
}

// ---------------------------------------------------------------- finish (+finalize, r6 verbatim)
__global__ __launch_bounds__(256) void finish_kernel(
    const float* __restrict__ z, const float* __restrict__ weight,
    const int4* __restrict__ candbuf,
    int* __restrict__ counts, double* __restrict__ loss_acc,
    int* __restrict__ done_ctr,
    float* __restrict__ out, float* __restrict__ out_scalars,
    float* __restrict__ out_idx_f)
{
    __shared__ int4  s_cand[32][8];
    __shared__ float s_zw[32][KDIM + 1];
    __shared__ int   s_fi[32];
    __shared__ double s_red[4];
    __shared__ int   s_last;

    const int i0 = blockIdx.x * 32;
    const int b  = i0 >> 12;
    const int s0 = i0 & (SPATIAL - 1);
    const int t  = threadIdx.x;

    s_cand[t >> 3][t & 7] = candbuf[(size_t)(i0 + (t >> 3)) * 8 + (t & 7)];

    for (int e = t; e < 32 * KDIM; e += 256) {
        const int c = e >> 5, rr = e & 31;
        s_zw[rr][c] = z[((size_t)b << 20) + ((size_t)c << 12) + s0 + rr];
    }
    __syncthreads();

    const int row = t >> 3, seg = t & 7;
    float zs[32];
#pragma unroll
    for (int j = 0; j < 32; j++) zs[j] = s_zw[row][seg * 32 + j];

    float da[16];
    float dmin_a = 3.4e38f;
#pragma unroll
    for (int sp = 0; sp < 8; sp++) {
        int4 c = s_cand[row][sp];
        da[sp * 2]     = 2048.0f - 2.0f * __uint_as_float((uint32_t)c.x & 0xFFFFFFC0u);
        da[sp * 2 + 1] = 2048.0f - 2.0f * __uint_as_float((uint32_t)c.z & 0xFFFFFFC0u);
        dmin_a = fminf(dmin_a, fminf(da[sp * 2], da[sp * 2 + 1]));
    }
    const float cutoff = dmin_a + 0.5f;

    double dbest = 1e300; int nbest = 0x7fffffff;
#pragma unroll 1
    for (int c = 0; c < 16; c++) {
        if (da[c] > cutoff) continue;
        int4 cc = s_cand[row][c >> 1];
        const int n = (c & 1) ? cc.w : cc.y;
        const float* wr = weight + (size_t)n * KDIM + seg * 32;
        double d = 0.0;
#pragma unroll
        for (int j = 0; j < 32; j++) {
            double df = (double)zs[j] - (double)wr[j];
            d += df * df;
        }
#pragma unroll
        for (int o = 1; o < 8; o <<= 1) d += __shfl_xor(d, o);
        if (d < dbest || (d == dbest && n < nbest)) { dbest = d; nbest = n; }
    }

    double lsum = 0.0;
    if (seg == 0) {
        s_fi[row] = nbest;
        out_idx_f[i0 + row] = (float)nbest;
        atomicAdd(&counts[nbest], 1);
        lsum = dbest;
    }
#pragma unroll
    for (int o = 1; o < 64; o <<= 1) lsum += __shfl_xor(lsum, o);
    if ((t & 63) == 0) s_red[t >> 6] = lsum;
    __syncthreads();
    if (t == 0) atomicAdd(loss_acc, s_red[0] + s_red[1] + s_red[2] + s_red[3]);

    for (int e = t; e < 32 * KDIM; e += 256) {
        const int rr = e >> 8, c = e & 255;
        s_zw[rr][c] = weight[(size_t)s_fi[rr] * KDIM + c];
    }
    __syncthreads();
    const int m = t & 31, c0 = t >> 5;
    const size_t obase = ((size_t)b << 20) + (size_t)(s0 + m);
    for (int c = c0; c < KDIM; c += 8)
        out[obase + ((size_t)c << 12)] = s_zw[m][c];

    if (t == 0) {
        __threadfence();
        int old = __hip_atomic_fetch_add(done_ctr, 1, __ATOMIC_ACQ_REL,
                                         __HIP_MEMORY_SCOPE_AGENT);
        s_last = (old == (int)gridDim.x - 1);
    }
    __syncthreads();
    if (s_last) {
        double s = 0.0;
        for (int n = t; n < N_CODES; n += 256) {
            int c = __hip_atomic_load(&counts[n], __ATOMIC_RELAXED,
                                      __HIP_MEMORY_SCOPE_AGENT);
            double p = (double)c / (double)M_TOTAL;
            s -= p * log(p + 1e-10);
        }
#pragma unroll
        for (int o = 32; o >= 1; o >>= 1) s += __shfl_xor(s, o);
        if ((t & 63) == 0) s_red[t >> 6] = s;
        __syncthreads();
        if (t == 0) {
            double tot = s_red[0] + s_red[1] + s_red[2] + s_red[3];
            double l = __hip_atomic_load(loss_acc, __ATOMIC_RELAXED,
                                         __HIP_MEMORY_SCOPE_AGENT);
            out_scalars[0] = (float)(0.25 * l / (double)(M_TOTAL * KDIM));
            out_scalars[1] = (float)exp(tot);
        }
    }
}

// ---------------------------------------------------------------- launch
extern "C" void kernel_launch(void* const* d_in, const int* in_sizes, int n_in,
                              void* d_out, int out_size, void* d_ws, size_t ws_size,
                              hipStream_t stream) {
    const float* z      = (const float*)d_in[0];   // 4*256*16*16*16 = 16.8 MB
    const float* weight = (const float*)d_in[1];   // 8192*256 = 8.4 MB
    float* out = (float*)d_out;

    size_t off = 0;
    auto carve = [&](size_t bytes) {
        void* p = (char*)d_ws + off;
        off += (bytes + 255) & ~(size_t)255;
        return p;
    };
    _Float16* wpk     = (_Float16*)carve((size_t)N_CODES * KDIM * 2);   // 4 MB
    float*    hw_arr  = (float*)   carve((size_t)N_CODES * 4);
    _Float16* zfrag   = (_Float16*)carve((size_t)M_TOTAL * KDIM * 2);   // 8 MB
    int4*     candbuf = (int4*)    carve((size_t)M_TOTAL * 8 * 16);     // 2 MB
    int*      counts  = (int*)     carve((size_t)N_CODES * 4);
    double*   lossac  = (double*)  carve(16);
    int*      donec   = (int*)     carve(16);

    float* out_scalars = out + (size_t)4 * KDIM * SPATIAL;   // [loss, perplexity]
    float* out_idx_f   = out_scalars + 2;                    // 16384 idx as float

    prep_kernel<<<dim3(2048 + 256), dim3(256), 0, stream>>>(
        weight, z, wpk, hw_arr, zfrag, counts, lossac, donec);
    gemm_kernel<<<dim3(128 * NSPLIT), dim3(256), 0, stream>>>(
        zfrag, wpk, hw_arr, candbuf);
    finish_kernel<<<dim3(M_TOTAL / 32), dim3(256), 0, stream>>>(
        z, weight, candbuf, counts, lossac, donec, out, out_scalars, out_idx_f);
}